// Round 2
// baseline (12863.332 us; speedup 1.0000x reference)
//
#include <hip/hip_runtime.h>

// GRU: B=32, T=16384, H=64, CIN=COUT=1.
// d_out = [ out (B*T floats) | states (B*T*H floats) ], fp32.
//
// R5: single-wave scan. H == wavefront size, so ONE wave per batch owns the
// entire recurrence with zero barriers and zero LDS:
//   - lane u holds h[u]; W_hh rows (u, 64+u, 128+u) live in 192 VGPRs
//     (48 NAMED float4s -- named to guarantee register residency, per the
//     R1 lesson that arrays get demoted to scratch).
//   - h all-gather = 64 v_readlane (register crossbar; no LDS round-trip,
//     no barrier -- R3/R4 post-mortem showed the step was bound by two LDS
//     latencies + barrier arrival spread, not by issue count).
//   - matvec = 192 fmaf in 3 interleaved chains (r,z,n): 6-cy issue spacing
//     per chain > 4-cy fmaf dep latency -> issue-bound, ~600 cy/step.
//   - x broadcast: one coalesced load per 64-step chunk into a register,
//     readlane per step; next chunk prefetched at chunk start.
//   - states store: fire-and-forget coalesced 256 B/step.

#define Bv   32
#define Tv   16384
#define Hv   64

__device__ __forceinline__ float bcast(float v, int k) {
    return __int_as_float(__builtin_amdgcn_readlane(__float_as_int(v), k));
}

// 4 k-values: 4 readlane + 12 fmaf, three independent accumulator chains.
#define DO4(WR, WZ, WN, K)                                            \
    do {                                                              \
        float hk;                                                     \
        hk = bcast(h, (K) + 0);                                       \
        ar = fmaf(WR.x, hk, ar);                                      \
        az = fmaf(WZ.x, hk, az);                                      \
        an = fmaf(WN.x, hk, an);                                      \
        hk = bcast(h, (K) + 1);                                       \
        ar = fmaf(WR.y, hk, ar);                                      \
        az = fmaf(WZ.y, hk, az);                                      \
        an = fmaf(WN.y, hk, an);                                      \
        hk = bcast(h, (K) + 2);                                       \
        ar = fmaf(WR.z, hk, ar);                                      \
        az = fmaf(WZ.z, hk, az);                                      \
        an = fmaf(WN.z, hk, an);                                      \
        hk = bcast(h, (K) + 3);                                       \
        ar = fmaf(WR.w, hk, ar);                                      \
        az = fmaf(WZ.w, hk, az);                                      \
        an = fmaf(WN.w, hk, an);                                      \
    } while (0)

__global__ __launch_bounds__(Hv, 1) void gru_scan(
    const float* __restrict__ x,      // [B,T]
    const float* __restrict__ W_ih,   // [192] (CIN=1)
    const float* __restrict__ W_hh,   // [192,64]
    const float* __restrict__ b_ih,   // [192]
    const float* __restrict__ b_hh,   // [192]
    float* __restrict__ states)       // [B,T,64]
{
    const int b = blockIdx.x;
    const int u = threadIdx.x;        // lane = hidden unit

    const float* xb = x + (size_t)b * Tv;
    float*       sb = states + (size_t)b * Tv * Hv;

    // W_hh rows u (r), 64+u (z), 128+u (n) -> 48 named float4 registers.
    const float4* Wr = reinterpret_cast<const float4*>(W_hh + (size_t)u * Hv);
    const float4* Wz = reinterpret_cast<const float4*>(W_hh + (size_t)(64 + u) * Hv);
    const float4* Wn = reinterpret_cast<const float4*>(W_hh + (size_t)(128 + u) * Hv);
    const float4 wr0 = Wr[0],  wr1 = Wr[1],  wr2 = Wr[2],  wr3 = Wr[3];
    const float4 wr4 = Wr[4],  wr5 = Wr[5],  wr6 = Wr[6],  wr7 = Wr[7];
    const float4 wr8 = Wr[8],  wr9 = Wr[9],  wr10 = Wr[10], wr11 = Wr[11];
    const float4 wr12 = Wr[12], wr13 = Wr[13], wr14 = Wr[14], wr15 = Wr[15];
    const float4 wz0 = Wz[0],  wz1 = Wz[1],  wz2 = Wz[2],  wz3 = Wz[3];
    const float4 wz4 = Wz[4],  wz5 = Wz[5],  wz6 = Wz[6],  wz7 = Wz[7];
    const float4 wz8 = Wz[8],  wz9 = Wz[9],  wz10 = Wz[10], wz11 = Wz[11];
    const float4 wz12 = Wz[12], wz13 = Wz[13], wz14 = Wz[14], wz15 = Wz[15];
    const float4 wn0 = Wn[0],  wn1 = Wn[1],  wn2 = Wn[2],  wn3 = Wn[3];
    const float4 wn4 = Wn[4],  wn5 = Wn[5],  wn6 = Wn[6],  wn7 = Wn[7];
    const float4 wn8 = Wn[8],  wn9 = Wn[9],  wn10 = Wn[10], wn11 = Wn[11];
    const float4 wn12 = Wn[12], wn13 = Wn[13], wn14 = Wn[14], wn15 = Wn[15];

    const float bhr = b_hh[u];
    const float bhz = b_hh[64 + u];
    const float bhn = b_hh[128 + u];
    const float wih_r = W_ih[u];
    const float wih_z = W_ih[64 + u];
    const float wih_n = W_ih[128 + u];
    const float bih_r = b_ih[u];
    const float bih_z = b_ih[64 + u];
    const float bih_n = b_ih[128 + u];

    float h  = 0.0f;
    float xv = xb[u];                 // x chunk for steps [0,64)

    for (int t0 = 0; t0 < Tv; t0 += 64) {
        // prefetch next x chunk (safe dummy index on the last chunk)
        const int tn = (t0 + 64 < Tv) ? (t0 + 64) : 0;
        const float xv_next = xb[tn + u];

#pragma unroll 1
        for (int tt = 0; tt < 64; ++tt) {
            const float xt  = bcast(xv, tt);
            const float ir  = fmaf(xt, wih_r, bih_r);
            const float iz  = fmaf(xt, wih_z, bih_z);
            const float in_ = fmaf(xt, wih_n, bih_n);

            float ar = bhr, az = bhz, an = bhn;
            DO4(wr0,  wz0,  wn0,   0);
            DO4(wr1,  wz1,  wn1,   4);
            DO4(wr2,  wz2,  wn2,   8);
            DO4(wr3,  wz3,  wn3,  12);
            DO4(wr4,  wz4,  wn4,  16);
            DO4(wr5,  wz5,  wn5,  20);
            DO4(wr6,  wz6,  wn6,  24);
            DO4(wr7,  wz7,  wn7,  28);
            DO4(wr8,  wz8,  wn8,  32);
            DO4(wr9,  wz9,  wn9,  36);
            DO4(wr10, wz10, wn10, 40);
            DO4(wr11, wz11, wn11, 44);
            DO4(wr12, wz12, wn12, 48);
            DO4(wr13, wz13, wn13, 52);
            DO4(wr14, wz14, wn14, 56);
            DO4(wr15, wz15, wn15, 60);

            const float r  = 1.0f / (1.0f + __expf(-(ir + ar)));
            const float z  = 1.0f / (1.0f + __expf(-(iz + az)));
            const float a  = fmaf(r, an, in_);
            const float e  = __expf(2.0f * a);          // tanh(a) = 1 - 2/(e+1)
            const float n  = 1.0f - 2.0f / (e + 1.0f);
            h = fmaf(z, h - n, n);                      // (1-z)*n + z*h

            sb[(size_t)(t0 + tt) * Hv + u] = h;         // fire-and-forget
        }
        xv = xv_next;
    }
}

// out[i] = states[i,:] . W_out + b_out + x[i],  i in [0, B*T)
__global__ __launch_bounds__(256) void gru_head(
    const float* __restrict__ x,
    const float* __restrict__ states,
    const float* __restrict__ W_out,   // [64]
    const float* __restrict__ b_out,   // [1]
    float* __restrict__ out)
{
    __shared__ float wsm[Hv];
    if (threadIdx.x < Hv) wsm[threadIdx.x] = W_out[threadIdx.x];
    __syncthreads();

    const int i = blockIdx.x * blockDim.x + threadIdx.x;
    if (i >= Bv * Tv) return;

    const float4* s4 = reinterpret_cast<const float4*>(states + (size_t)i * Hv);
    float acc = 0.0f;
#pragma unroll
    for (int k = 0; k < Hv / 4; ++k) {
        const float4 v = s4[k];
        acc = fmaf(v.x, wsm[4*k+0], acc);
        acc = fmaf(v.y, wsm[4*k+1], acc);
        acc = fmaf(v.z, wsm[4*k+2], acc);
        acc = fmaf(v.w, wsm[4*k+3], acc);
    }
    out[i] = acc + b_out[0] + x[i];
}

extern "C" void kernel_launch(void* const* d_in, const int* in_sizes, int n_in,
                              void* d_out, int out_size, void* d_ws, size_t ws_size,
                              hipStream_t stream) {
    const float* x     = (const float*)d_in[0];   // [B,T,1]
    const float* W_ih  = (const float*)d_in[1];   // [192,1]
    const float* W_hh  = (const float*)d_in[2];   // [192,64]
    const float* b_ih  = (const float*)d_in[3];   // [192]
    const float* b_hh  = (const float*)d_in[4];   // [192]
    const float* W_out = (const float*)d_in[5];   // [1,64]
    const float* b_out = (const float*)d_in[6];   // [1]

    float* out    = (float*)d_out;                // [B*T]
    float* states = out + (size_t)Bv * Tv;        // [B*T*H]

    gru_scan<<<Bv, Hv, 0, stream>>>(x, W_ih, W_hh, b_ih, b_hh, states);
    gru_head<<<(Bv * Tv + 255) / 256, 256, 0, stream>>>(x, states, W_out, b_out, out);
}

// Round 5
// 12836.797 us; speedup vs baseline: 1.0021x; 1.0021x over previous
//
#include <hip/hip_runtime.h>

// GRU: B=32, T=16384, H=64, CIN=COUT=1.
// d_out = [ out (B*T floats) | states (B*T*H floats) ], fp32.
//
// R6 (second resubmit -- rounds 3 & 4 both died with GPUAcquisitionTimeout,
// the kernel has never executed).
// R5 (single-wave, zero-barrier, zero-LDS scan) + forced VGPR residency.
// R5 post-mortem: VGPR_Count=112 showed the allocator REMATERIALIZED the 48
// loop-invariant weight loads inside the step loop (48 KB > L1 -> L2 misses
// every step, VALUBusy 2.1%). Fix: pass the 48 float4s through empty
// asm volatile "+v" barriers after loading -- opaque values can't be
// rematerialized, so they must stay in registers (~225 VGPRs < 256 budget).

#define Bv   32
#define Tv   16384
#define Hv   64

typedef float f32x4 __attribute__((ext_vector_type(4)));

__device__ __forceinline__ float bcast(float v, int k) {
    return __int_as_float(__builtin_amdgcn_readlane(__float_as_int(v), k));
}

// 4 k-values: 4 readlane (imm lane) + 12 fmaf, three independent chains.
#define DO4(WR, WZ, WN, K)                                            \
    do {                                                              \
        float hk;                                                     \
        hk = bcast(h, (K) + 0);                                       \
        ar = fmaf(WR.x, hk, ar);                                      \
        az = fmaf(WZ.x, hk, az);                                      \
        an = fmaf(WN.x, hk, an);                                      \
        hk = bcast(h, (K) + 1);                                       \
        ar = fmaf(WR.y, hk, ar);                                      \
        az = fmaf(WZ.y, hk, az);                                      \
        an = fmaf(WN.y, hk, an);                                      \
        hk = bcast(h, (K) + 2);                                       \
        ar = fmaf(WR.z, hk, ar);                                      \
        az = fmaf(WZ.z, hk, az);                                      \
        an = fmaf(WN.z, hk, an);                                      \
        hk = bcast(h, (K) + 3);                                       \
        ar = fmaf(WR.w, hk, ar);                                      \
        az = fmaf(WZ.w, hk, az);                                      \
        an = fmaf(WN.w, hk, an);                                      \
    } while (0)

__global__ __launch_bounds__(Hv, 1) void gru_scan(
    const float* __restrict__ x,      // [B,T]
    const float* __restrict__ W_ih,   // [192] (CIN=1)
    const float* __restrict__ W_hh,   // [192,64]
    const float* __restrict__ b_ih,   // [192]
    const float* __restrict__ b_hh,   // [192]
    float* __restrict__ states)       // [B,T,64]
{
    const int b = blockIdx.x;
    const int u = threadIdx.x;        // lane = hidden unit

    const float* xb = x + (size_t)b * Tv;
    float*       sb = states + (size_t)b * Tv * Hv;

    // W_hh rows u (r), 64+u (z), 128+u (n) -> 48 float4 registers.
    const f32x4* Wr = reinterpret_cast<const f32x4*>(W_hh + (size_t)u * Hv);
    const f32x4* Wz = reinterpret_cast<const f32x4*>(W_hh + (size_t)(64 + u) * Hv);
    const f32x4* Wn = reinterpret_cast<const f32x4*>(W_hh + (size_t)(128 + u) * Hv);
    f32x4 wr0 = Wr[0],  wr1 = Wr[1],  wr2 = Wr[2],  wr3 = Wr[3];
    f32x4 wr4 = Wr[4],  wr5 = Wr[5],  wr6 = Wr[6],  wr7 = Wr[7];
    f32x4 wr8 = Wr[8],  wr9 = Wr[9],  wr10 = Wr[10], wr11 = Wr[11];
    f32x4 wr12 = Wr[12], wr13 = Wr[13], wr14 = Wr[14], wr15 = Wr[15];
    f32x4 wz0 = Wz[0],  wz1 = Wz[1],  wz2 = Wz[2],  wz3 = Wz[3];
    f32x4 wz4 = Wz[4],  wz5 = Wz[5],  wz6 = Wz[6],  wz7 = Wz[7];
    f32x4 wz8 = Wz[8],  wz9 = Wz[9],  wz10 = Wz[10], wz11 = Wz[11];
    f32x4 wz12 = Wz[12], wz13 = Wz[13], wz14 = Wz[14], wz15 = Wz[15];
    f32x4 wn0 = Wn[0],  wn1 = Wn[1],  wn2 = Wn[2],  wn3 = Wn[3];
    f32x4 wn4 = Wn[4],  wn5 = Wn[5],  wn6 = Wn[6],  wn7 = Wn[7];
    f32x4 wn8 = Wn[8],  wn9 = Wn[9],  wn10 = Wn[10], wn11 = Wn[11];
    f32x4 wn12 = Wn[12], wn13 = Wn[13], wn14 = Wn[14], wn15 = Wn[15];

    // Opacity barriers: forbid rematerialization of the weight loads.
    asm volatile("" : "+v"(wr0), "+v"(wr1), "+v"(wr2),  "+v"(wr3),
                      "+v"(wr4), "+v"(wr5), "+v"(wr6),  "+v"(wr7),
                      "+v"(wr8), "+v"(wr9), "+v"(wr10), "+v"(wr11),
                      "+v"(wr12), "+v"(wr13), "+v"(wr14), "+v"(wr15));
    asm volatile("" : "+v"(wz0), "+v"(wz1), "+v"(wz2),  "+v"(wz3),
                      "+v"(wz4), "+v"(wz5), "+v"(wz6),  "+v"(wz7),
                      "+v"(wz8), "+v"(wz9), "+v"(wz10), "+v"(wz11),
                      "+v"(wz12), "+v"(wz13), "+v"(wz14), "+v"(wz15));
    asm volatile("" : "+v"(wn0), "+v"(wn1), "+v"(wn2),  "+v"(wn3),
                      "+v"(wn4), "+v"(wn5), "+v"(wn6),  "+v"(wn7),
                      "+v"(wn8), "+v"(wn9), "+v"(wn10), "+v"(wn11),
                      "+v"(wn12), "+v"(wn13), "+v"(wn14), "+v"(wn15));

    const float bhr = b_hh[u];
    const float bhz = b_hh[64 + u];
    const float bhn = b_hh[128 + u];
    const float wih_r = W_ih[u];
    const float wih_z = W_ih[64 + u];
    const float wih_n = W_ih[128 + u];
    const float bih_r = b_ih[u];
    const float bih_z = b_ih[64 + u];
    const float bih_n = b_ih[128 + u];

    float h  = 0.0f;
    float xv = xb[u];                 // x chunk for steps [0,64)

    for (int t0 = 0; t0 < Tv; t0 += 64) {
        // prefetch next x chunk (safe dummy index on the last chunk)
        const int tn = (t0 + 64 < Tv) ? (t0 + 64) : 0;
        const float xv_next = xb[tn + u];

#pragma unroll 1
        for (int tt = 0; tt < 64; ++tt) {
            const float xt  = bcast(xv, tt);
            const float ir  = fmaf(xt, wih_r, bih_r);
            const float iz  = fmaf(xt, wih_z, bih_z);
            const float in_ = fmaf(xt, wih_n, bih_n);

            float ar = bhr, az = bhz, an = bhn;
            DO4(wr0,  wz0,  wn0,   0);
            DO4(wr1,  wz1,  wn1,   4);
            DO4(wr2,  wz2,  wn2,   8);
            DO4(wr3,  wz3,  wn3,  12);
            DO4(wr4,  wz4,  wn4,  16);
            DO4(wr5,  wz5,  wn5,  20);
            DO4(wr6,  wz6,  wn6,  24);
            DO4(wr7,  wz7,  wn7,  28);
            DO4(wr8,  wz8,  wn8,  32);
            DO4(wr9,  wz9,  wn9,  36);
            DO4(wr10, wz10, wn10, 40);
            DO4(wr11, wz11, wn11, 44);
            DO4(wr12, wz12, wn12, 48);
            DO4(wr13, wz13, wn13, 52);
            DO4(wr14, wz14, wn14, 56);
            DO4(wr15, wz15, wn15, 60);

            const float r  = 1.0f / (1.0f + __expf(-(ir + ar)));
            const float z  = 1.0f / (1.0f + __expf(-(iz + az)));
            const float a  = fmaf(r, an, in_);
            const float e  = __expf(2.0f * a);          // tanh(a) = 1 - 2/(e+1)
            const float n  = 1.0f - 2.0f / (e + 1.0f);
            h = fmaf(z, h - n, n);                      // (1-z)*n + z*h

            sb[(size_t)(t0 + tt) * Hv + u] = h;         // fire-and-forget
        }
        xv = xv_next;
    }
}

// out[i] = states[i,:] . W_out + b_out + x[i],  i in [0, B*T)
__global__ __launch_bounds__(256) void gru_head(
    const float* __restrict__ x,
    const float* __restrict__ states,
    const float* __restrict__ W_out,   // [64]
    const float* __restrict__ b_out,   // [1]
    float* __restrict__ out)
{
    __shared__ float wsm[Hv];
    if (threadIdx.x < Hv) wsm[threadIdx.x] = W_out[threadIdx.x];
    __syncthreads();

    const int i = blockIdx.x * blockDim.x + threadIdx.x;
    if (i >= Bv * Tv) return;

    const float4* s4 = reinterpret_cast<const float4*>(states + (size_t)i * Hv);
    float acc = 0.0f;
#pragma unroll
    for (int k = 0; k < Hv / 4; ++k) {
        const float4 v = s4[k];
        acc = fmaf(v.x, wsm[4*k+0], acc);
        acc = fmaf(v.y, wsm[4*k+1], acc);
        acc = fmaf(v.z, wsm[4*k+2], acc);
        acc = fmaf(v.w, wsm[4*k+3], acc);
    }
    out[i] = acc + b_out[0] + x[i];
}

extern "C" void kernel_launch(void* const* d_in, const int* in_sizes, int n_in,
                              void* d_out, int out_size, void* d_ws, size_t ws_size,
                              hipStream_t stream) {
    const float* x     = (const float*)d_in[0];   // [B,T,1]
    const float* W_ih  = (const float*)d_in[1];   // [192,1]
    const float* W_hh  = (const float*)d_in[2];   // [192,64]
    const float* b_ih  = (const float*)d_in[3];   // [192]
    const float* b_hh  = (const float*)d_in[4];   // [192]
    const float* W_out = (const float*)d_in[5];   // [1,64]
    const float* b_out = (const float*)d_in[6];   // [1]

    float* out    = (float*)d_out;                // [B*T]
    float* states = out + (size_t)Bv * Tv;        // [B*T*H]

    gru_scan<<<Bv, Hv, 0, stream>>>(x, W_ih, W_hh, b_ih, b_hh, states);
    gru_head<<<(Bv * Tv + 255) / 256, 256, 0, stream>>>(x, states, W_out, b_out, out);
}

// Round 6
// 12821.439 us; speedup vs baseline: 1.0033x; 1.0012x over previous
//
#include <hip/hip_runtime.h>

// GRU: B=32, T=16384, H=64, CIN=COUT=1.
// d_out = [ out (B*T floats) | states (B*T*H floats) ], fp32.
//
// R7 = R6 + amdgpu_waves_per_eu(1,1).
// R6 post-mortem: VGPR_Count stayed 112 and timing matched R5 exactly -- the
// opacity barriers blocked rematerialization but the allocator SPILLED the
// weight values to scratch instead (reloads are L1/L2-cached -> same cost as
// R5's remat). Root cause: HIP __launch_bounds__'s 2nd arg is only a MIN
// waves/EU (no constraint); the allocator still targets a multi-wave
// occupancy tier and caps pressure at <=128 VGPRs. Fix: pin waves/EU to
// [1,1] so there is no occupancy benefit to spilling -- the 48 weight
// float4s (192 VGPRs) can then stay resident (~220 < 512 budget).

#define Bv   32
#define Tv   16384
#define Hv   64

typedef float f32x4 __attribute__((ext_vector_type(4)));

__device__ __forceinline__ float bcast(float v, int k) {
    return __int_as_float(__builtin_amdgcn_readlane(__float_as_int(v), k));
}

// 4 k-values: 4 readlane (imm lane) + 12 fmaf, three independent chains.
#define DO4(WR, WZ, WN, K)                                            \
    do {                                                              \
        float hk;                                                     \
        hk = bcast(h, (K) + 0);                                       \
        ar = fmaf(WR.x, hk, ar);                                      \
        az = fmaf(WZ.x, hk, az);                                      \
        an = fmaf(WN.x, hk, an);                                      \
        hk = bcast(h, (K) + 1);                                       \
        ar = fmaf(WR.y, hk, ar);                                      \
        az = fmaf(WZ.y, hk, az);                                      \
        an = fmaf(WN.y, hk, an);                                      \
        hk = bcast(h, (K) + 2);                                       \
        ar = fmaf(WR.z, hk, ar);                                      \
        az = fmaf(WZ.z, hk, az);                                      \
        an = fmaf(WN.z, hk, an);                                      \
        hk = bcast(h, (K) + 3);                                       \
        ar = fmaf(WR.w, hk, ar);                                      \
        az = fmaf(WZ.w, hk, az);                                      \
        an = fmaf(WN.w, hk, an);                                      \
    } while (0)

__global__ __launch_bounds__(Hv)
__attribute__((amdgpu_waves_per_eu(1, 1)))
void gru_scan(
    const float* __restrict__ x,      // [B,T]
    const float* __restrict__ W_ih,   // [192] (CIN=1)
    const float* __restrict__ W_hh,   // [192,64]
    const float* __restrict__ b_ih,   // [192]
    const float* __restrict__ b_hh,   // [192]
    float* __restrict__ states)       // [B,T,64]
{
    const int b = blockIdx.x;
    const int u = threadIdx.x;        // lane = hidden unit

    const float* xb = x + (size_t)b * Tv;
    float*       sb = states + (size_t)b * Tv * Hv;

    // W_hh rows u (r), 64+u (z), 128+u (n) -> 48 float4 registers.
    const f32x4* Wr = reinterpret_cast<const f32x4*>(W_hh + (size_t)u * Hv);
    const f32x4* Wz = reinterpret_cast<const f32x4*>(W_hh + (size_t)(64 + u) * Hv);
    const f32x4* Wn = reinterpret_cast<const f32x4*>(W_hh + (size_t)(128 + u) * Hv);
    f32x4 wr0 = Wr[0],  wr1 = Wr[1],  wr2 = Wr[2],  wr3 = Wr[3];
    f32x4 wr4 = Wr[4],  wr5 = Wr[5],  wr6 = Wr[6],  wr7 = Wr[7];
    f32x4 wr8 = Wr[8],  wr9 = Wr[9],  wr10 = Wr[10], wr11 = Wr[11];
    f32x4 wr12 = Wr[12], wr13 = Wr[13], wr14 = Wr[14], wr15 = Wr[15];
    f32x4 wz0 = Wz[0],  wz1 = Wz[1],  wz2 = Wz[2],  wz3 = Wz[3];
    f32x4 wz4 = Wz[4],  wz5 = Wz[5],  wz6 = Wz[6],  wz7 = Wz[7];
    f32x4 wz8 = Wz[8],  wz9 = Wz[9],  wz10 = Wz[10], wz11 = Wz[11];
    f32x4 wz12 = Wz[12], wz13 = Wz[13], wz14 = Wz[14], wz15 = Wz[15];
    f32x4 wn0 = Wn[0],  wn1 = Wn[1],  wn2 = Wn[2],  wn3 = Wn[3];
    f32x4 wn4 = Wn[4],  wn5 = Wn[5],  wn6 = Wn[6],  wn7 = Wn[7];
    f32x4 wn8 = Wn[8],  wn9 = Wn[9],  wn10 = Wn[10], wn11 = Wn[11];
    f32x4 wn12 = Wn[12], wn13 = Wn[13], wn14 = Wn[14], wn15 = Wn[15];

    // Opacity barriers: forbid rematerialization of the weight loads.
    asm volatile("" : "+v"(wr0), "+v"(wr1), "+v"(wr2),  "+v"(wr3),
                      "+v"(wr4), "+v"(wr5), "+v"(wr6),  "+v"(wr7),
                      "+v"(wr8), "+v"(wr9), "+v"(wr10), "+v"(wr11),
                      "+v"(wr12), "+v"(wr13), "+v"(wr14), "+v"(wr15));
    asm volatile("" : "+v"(wz0), "+v"(wz1), "+v"(wz2),  "+v"(wz3),
                      "+v"(wz4), "+v"(wz5), "+v"(wz6),  "+v"(wz7),
                      "+v"(wz8), "+v"(wz9), "+v"(wz10), "+v"(wz11),
                      "+v"(wz12), "+v"(wz13), "+v"(wz14), "+v"(wz15));
    asm volatile("" : "+v"(wn0), "+v"(wn1), "+v"(wn2),  "+v"(wn3),
                      "+v"(wn4), "+v"(wn5), "+v"(wn6),  "+v"(wn7),
                      "+v"(wn8), "+v"(wn9), "+v"(wn10), "+v"(wn11),
                      "+v"(wn12), "+v"(wn13), "+v"(wn14), "+v"(wn15));

    const float bhr = b_hh[u];
    const float bhz = b_hh[64 + u];
    const float bhn = b_hh[128 + u];
    const float wih_r = W_ih[u];
    const float wih_z = W_ih[64 + u];
    const float wih_n = W_ih[128 + u];
    const float bih_r = b_ih[u];
    const float bih_z = b_ih[64 + u];
    const float bih_n = b_ih[128 + u];

    float h  = 0.0f;
    float xv = xb[u];                 // x chunk for steps [0,64)

    for (int t0 = 0; t0 < Tv; t0 += 64) {
        // prefetch next x chunk (safe dummy index on the last chunk)
        const int tn = (t0 + 64 < Tv) ? (t0 + 64) : 0;
        const float xv_next = xb[tn + u];

#pragma unroll 1
        for (int tt = 0; tt < 64; ++tt) {
            const float xt  = bcast(xv, tt);
            const float ir  = fmaf(xt, wih_r, bih_r);
            const float iz  = fmaf(xt, wih_z, bih_z);
            const float in_ = fmaf(xt, wih_n, bih_n);

            float ar = bhr, az = bhz, an = bhn;
            DO4(wr0,  wz0,  wn0,   0);
            DO4(wr1,  wz1,  wn1,   4);
            DO4(wr2,  wz2,  wn2,   8);
            DO4(wr3,  wz3,  wn3,  12);
            DO4(wr4,  wz4,  wn4,  16);
            DO4(wr5,  wz5,  wn5,  20);
            DO4(wr6,  wz6,  wn6,  24);
            DO4(wr7,  wz7,  wn7,  28);
            DO4(wr8,  wz8,  wn8,  32);
            DO4(wr9,  wz9,  wn9,  36);
            DO4(wr10, wz10, wn10, 40);
            DO4(wr11, wz11, wn11, 44);
            DO4(wr12, wz12, wn12, 48);
            DO4(wr13, wz13, wn13, 52);
            DO4(wr14, wz14, wn14, 56);
            DO4(wr15, wz15, wn15, 60);

            const float r  = 1.0f / (1.0f + __expf(-(ir + ar)));
            const float z  = 1.0f / (1.0f + __expf(-(iz + az)));
            const float a  = fmaf(r, an, in_);
            const float e  = __expf(2.0f * a);          // tanh(a) = 1 - 2/(e+1)
            const float n  = 1.0f - 2.0f / (e + 1.0f);
            h = fmaf(z, h - n, n);                      // (1-z)*n + z*h

            sb[(size_t)(t0 + tt) * Hv + u] = h;         // fire-and-forget
        }
        xv = xv_next;
    }
}

// out[i] = states[i,:] . W_out + b_out + x[i],  i in [0, B*T)
__global__ __launch_bounds__(256) void gru_head(
    const float* __restrict__ x,
    const float* __restrict__ states,
    const float* __restrict__ W_out,   // [64]
    const float* __restrict__ b_out,   // [1]
    float* __restrict__ out)
{
    __shared__ float wsm[Hv];
    if (threadIdx.x < Hv) wsm[threadIdx.x] = W_out[threadIdx.x];
    __syncthreads();

    const int i = blockIdx.x * blockDim.x + threadIdx.x;
    if (i >= Bv * Tv) return;

    const float4* s4 = reinterpret_cast<const float4*>(states + (size_t)i * Hv);
    float acc = 0.0f;
#pragma unroll
    for (int k = 0; k < Hv / 4; ++k) {
        const float4 v = s4[k];
        acc = fmaf(v.x, wsm[4*k+0], acc);
        acc = fmaf(v.y, wsm[4*k+1], acc);
        acc = fmaf(v.z, wsm[4*k+2], acc);
        acc = fmaf(v.w, wsm[4*k+3], acc);
    }
    out[i] = acc + b_out[0] + x[i];
}

extern "C" void kernel_launch(void* const* d_in, const int* in_sizes, int n_in,
                              void* d_out, int out_size, void* d_ws, size_t ws_size,
                              hipStream_t stream) {
    const float* x     = (const float*)d_in[0];   // [B,T,1]
    const float* W_ih  = (const float*)d_in[1];   // [192,1]
    const float* W_hh  = (const float*)d_in[2];   // [192,64]
    const float* b_ih  = (const float*)d_in[3];   // [192]
    const float* b_hh  = (const float*)d_in[4];   // [192]
    const float* W_out = (const float*)d_in[5];   // [1,64]
    const float* b_out = (const float*)d_in[6];   // [1]

    float* out    = (float*)d_out;                // [B*T]
    float* states = out + (size_t)Bv * Tv;        // [B*T*H]

    gru_scan<<<Bv, Hv, 0, stream>>>(x, W_ih, W_hh, b_ih, b_hh, states);
    gru_head<<<(Bv * Tv + 255) / 256, 256, 0, stream>>>(x, states, W_out, b_out, out);
}

// Round 7
// 12295.300 us; speedup vs baseline: 1.0462x; 1.0428x over previous
//
#include <hip/hip_runtime.h>

// GRU: B=32, T=16384, H=64, CIN=COUT=1.
// d_out = [ out (B*T floats) | states (B*T*H floats) ], fp32.
//
// R8: single-wave scan (R5 structure) with W_hh in LDS.
// R5-R7 post-mortem: the allocator refuses to keep 48 weight float4s
// resident (VGPR_Count 112/132 across opacity barriers + waves_per_eu(1,1));
// it spills & reloads per step, and 48KB/wave misses L1 every step
// (~1860 cy steps, VALUBusy 2.1%). So: stop fighting the allocator.
//   - W_hh staged ONCE into 48 KB LDS, float4-slot XOR-swizzled
//     (slot = r*16 + (j ^ (r&7))) -> conflict-free ds_read_b128
//     (row-major would be 32-way: rows are 256B apart = same bank).
//   - per-iteration opaque off=0 (asm "+v" on an INDEX, keeping the
//     addrspace(3) base) blocks LICM from hoisting the loop-invariant
//     LDS loads and re-creating the spill.
//   - h all-gather stays the 64-readlane register crossbar (no barrier,
//     no LDS round-trip on the h-dependent path).
//   - x chunk in a register, one readlane per step; states stores
//     fire-and-forget coalesced 256 B.

#define Bv   32
#define Tv   16384
#define Hv   64

typedef float f32x4 __attribute__((ext_vector_type(4)));

__device__ __forceinline__ float bcast(float v, int k) {
    return __int_as_float(__builtin_amdgcn_readlane(__float_as_int(v), k));
}

// 4 k-values: 4 readlane (imm lane) + 12 fmaf, three independent chains.
#define DO4(WR, WZ, WN, K)                                            \
    do {                                                              \
        float hk;                                                     \
        hk = bcast(h, (K) + 0);                                       \
        ar = fmaf(WR.x, hk, ar);                                      \
        az = fmaf(WZ.x, hk, az);                                      \
        an = fmaf(WN.x, hk, an);                                      \
        hk = bcast(h, (K) + 1);                                       \
        ar = fmaf(WR.y, hk, ar);                                      \
        az = fmaf(WZ.y, hk, az);                                      \
        an = fmaf(WN.y, hk, an);                                      \
        hk = bcast(h, (K) + 2);                                       \
        ar = fmaf(WR.z, hk, ar);                                      \
        az = fmaf(WZ.z, hk, az);                                      \
        an = fmaf(WN.z, hk, an);                                      \
        hk = bcast(h, (K) + 3);                                       \
        ar = fmaf(WR.w, hk, ar);                                      \
        az = fmaf(WZ.w, hk, az);                                      \
        an = fmaf(WN.w, hk, an);                                      \
    } while (0)

// load the swizzled float4 of row-base RB (element index) at logical col J
#define LW(RB, J)  lw[(RB) + ((J) ^ x7) + off]

__global__ __launch_bounds__(Hv, 1) void gru_scan(
    const float* __restrict__ x,      // [B,T]
    const float* __restrict__ W_ih,   // [192] (CIN=1)
    const float* __restrict__ W_hh,   // [192,64]
    const float* __restrict__ b_ih,   // [192]
    const float* __restrict__ b_hh,   // [192]
    float* __restrict__ states)       // [B,T,64]
{
    const int b  = blockIdx.x;
    const int u  = threadIdx.x;       // lane = hidden unit
    const int x7 = u & 7;             // swizzle key (same for rows u,64+u,128+u)
    const int r0 = u << 4;            // element base of row u
    const int r1 = r0 + 1024;         // row 64+u
    const int r2 = r0 + 2048;         // row 128+u

    __shared__ f32x4 lw[3072];        // 48 KB swizzled W_hh

    const float* xb = x + (size_t)b * Tv;
    float*       sb = states + (size_t)b * Tv * Hv;

    // ---- one-time stage: W_hh -> LDS, XOR-swizzled slots ----
    // single wave: no barrier needed; compiler orders ds_write -> ds_read.
    const f32x4* Wg = reinterpret_cast<const f32x4*>(W_hh);
    for (int idx = u; idx < 3072; idx += 64) {
        const int r = idx >> 4, j = idx & 15;
        lw[(r << 4) + (j ^ (r & 7))] = Wg[idx];
    }

    const float bhr = b_hh[u];
    const float bhz = b_hh[64 + u];
    const float bhn = b_hh[128 + u];
    const float wih_r = W_ih[u];
    const float wih_z = W_ih[64 + u];
    const float wih_n = W_ih[128 + u];
    const float bih_r = b_ih[u];
    const float bih_z = b_ih[64 + u];
    const float bih_n = b_ih[128 + u];

    float h  = 0.0f;
    float xv = xb[u];                 // x chunk for steps [0,64)

    for (int t0 = 0; t0 < Tv; t0 += 64) {
        // prefetch next x chunk (safe dummy index on the last chunk)
        const int tn = (t0 + 64 < Tv) ? (t0 + 64) : 0;
        const float xv_next = xb[tn + u];

#pragma unroll 1
        for (int tt = 0; tt < 64; ++tt) {
            // opaque zero index: blocks LICM/CSE of the weight reads
            // (an opaque POINTER would lose addrspace(3) -> flat_load)
            int off = 0;
            asm volatile("" : "+v"(off));

            const float xt  = bcast(xv, tt);
            const float ir  = fmaf(xt, wih_r, bih_r);
            const float iz  = fmaf(xt, wih_z, bih_z);
            const float in_ = fmaf(xt, wih_n, bih_n);

            float ar = bhr, az = bhz, an = bhn;
            {
                const f32x4 a0 = LW(r0, 0),  b0 = LW(r1, 0),  c0 = LW(r2, 0);
                DO4(a0, b0, c0, 0);
                const f32x4 a1 = LW(r0, 1),  b1 = LW(r1, 1),  c1 = LW(r2, 1);
                DO4(a1, b1, c1, 4);
                const f32x4 a2 = LW(r0, 2),  b2 = LW(r1, 2),  c2 = LW(r2, 2);
                DO4(a2, b2, c2, 8);
                const f32x4 a3 = LW(r0, 3),  b3 = LW(r1, 3),  c3 = LW(r2, 3);
                DO4(a3, b3, c3, 12);
                const f32x4 a4 = LW(r0, 4),  b4 = LW(r1, 4),  c4 = LW(r2, 4);
                DO4(a4, b4, c4, 16);
                const f32x4 a5 = LW(r0, 5),  b5 = LW(r1, 5),  c5 = LW(r2, 5);
                DO4(a5, b5, c5, 20);
                const f32x4 a6 = LW(r0, 6),  b6 = LW(r1, 6),  c6 = LW(r2, 6);
                DO4(a6, b6, c6, 24);
                const f32x4 a7 = LW(r0, 7),  b7 = LW(r1, 7),  c7 = LW(r2, 7);
                DO4(a7, b7, c7, 28);
                const f32x4 a8 = LW(r0, 8),  b8 = LW(r1, 8),  c8 = LW(r2, 8);
                DO4(a8, b8, c8, 32);
                const f32x4 a9 = LW(r0, 9),  b9 = LW(r1, 9),  c9 = LW(r2, 9);
                DO4(a9, b9, c9, 36);
                const f32x4 aa = LW(r0,10),  ba = LW(r1,10),  ca = LW(r2,10);
                DO4(aa, ba, ca, 40);
                const f32x4 ab = LW(r0,11),  bb = LW(r1,11),  cb = LW(r2,11);
                DO4(ab, bb, cb, 44);
                const f32x4 ac = LW(r0,12),  bc = LW(r1,12),  cc = LW(r2,12);
                DO4(ac, bc, cc, 48);
                const f32x4 ad = LW(r0,13),  bd = LW(r1,13),  cd = LW(r2,13);
                DO4(ad, bd, cd, 52);
                const f32x4 ae = LW(r0,14),  be = LW(r1,14),  ce = LW(r2,14);
                DO4(ae, be, ce, 56);
                const f32x4 af = LW(r0,15),  bf = LW(r1,15),  cf = LW(r2,15);
                DO4(af, bf, cf, 60);
            }

            const float r  = 1.0f / (1.0f + __expf(-(ir + ar)));
            const float z  = 1.0f / (1.0f + __expf(-(iz + az)));
            const float a  = fmaf(r, an, in_);
            const float e  = __expf(2.0f * a);          // tanh(a) = 1 - 2/(e+1)
            const float n  = 1.0f - 2.0f / (e + 1.0f);
            h = fmaf(z, h - n, n);                      // (1-z)*n + z*h

            sb[(size_t)(t0 + tt) * Hv + u] = h;         // fire-and-forget
        }
        xv = xv_next;
    }
}

// out[i] = states[i,:] . W_out + b_out + x[i],  i in [0, B*T)
__global__ __launch_bounds__(256) void gru_head(
    const float* __restrict__ x,
    const float* __restrict__ states,
    const float* __restrict__ W_out,   // [64]
    const float* __restrict__ b_out,   // [1]
    float* __restrict__ out)
{
    __shared__ float wsm[Hv];
    if (threadIdx.x < Hv) wsm[threadIdx.x] = W_out[threadIdx.x];
    __syncthreads();

    const int i = blockIdx.x * blockDim.x + threadIdx.x;
    if (i >= Bv * Tv) return;

    const float4* s4 = reinterpret_cast<const float4*>(states + (size_t)i * Hv);
    float acc = 0.0f;
#pragma unroll
    for (int k = 0; k < Hv / 4; ++k) {
        const float4 v = s4[k];
        acc = fmaf(v.x, wsm[4*k+0], acc);
        acc = fmaf(v.y, wsm[4*k+1], acc);
        acc = fmaf(v.z, wsm[4*k+2], acc);
        acc = fmaf(v.w, wsm[4*k+3], acc);
    }
    out[i] = acc + b_out[0] + x[i];
}

extern "C" void kernel_launch(void* const* d_in, const int* in_sizes, int n_in,
                              void* d_out, int out_size, void* d_ws, size_t ws_size,
                              hipStream_t stream) {
    const float* x     = (const float*)d_in[0];   // [B,T,1]
    const float* W_ih  = (const float*)d_in[1];   // [192,1]
    const float* W_hh  = (const float*)d_in[2];   // [192,64]
    const float* b_ih  = (const float*)d_in[3];   // [192]
    const float* b_hh  = (const float*)d_in[4];   // [192]
    const float* W_out = (const float*)d_in[5];   // [1,64]
    const float* b_out = (const float*)d_in[6];   // [1]

    float* out    = (float*)d_out;                // [B*T]
    float* states = out + (size_t)Bv * Tv;        // [B*T*H]

    gru_scan<<<Bv, Hv, 0, stream>>>(x, W_ih, W_hh, b_ih, b_hh, states);
    gru_head<<<(Bv * Tv + 255) / 256, 256, 0, stream>>>(x, states, W_out, b_out, out);
}

// Round 8
// 6791.296 us; speedup vs baseline: 1.8941x; 1.8104x over previous
//
#include <hip/hip_runtime.h>

// GRU: B=32, T=16384, H=64, CIN=COUT=1.
// d_out = [ out (B*T floats) | states (B*T*H floats) ], fp32.
//
// R9: 3 waves (wave = gate), lane = unit, readlane h-crossbar.
//   - Each lane holds ONE W_hh row in 16 named float4s = 64 VGPRs --
//     the pressure level R3 proved stays register-resident (VGPR=72).
//     (R5-R8: 192 floats/lane always spilled; 48 KB LDS weights hit a
//     ~576cy/step LDS-pipe serialization floor. Both dead ends.)
//   - All 3 waves redundantly compute h (lane u holds h[u]) -> each wave
//     broadcasts h with its own 64 v_readlane (register crossbar): no LDS
//     h-copy, no ds_write/ds_read of h on the critical path.
//   - Only LDS: 3x64-float gate exchange, double-buffered, ONE lgkm-only
//     barrier per step (no __syncthreads: that drains vmcnt and would
//     stall on the fire-and-forget state stores -- R3's hidden tax).
//   - Exchange layout [2][3][64]: write stride-1 conflict-free, read 3x
//     stride-1 conflict-free (R8's 1e8-conflict swizzle lesson: verify
//     bank math, keep it linear).

#define Bv   32
#define Tv   16384
#define Hv   64

__device__ __forceinline__ float bcast(float v, int k) {
    return __int_as_float(__builtin_amdgcn_readlane(__float_as_int(v), k));
}

// LDS-only barrier: drain lgkmcnt (ghs write visible), raw s_barrier.
__device__ __forceinline__ void lds_barrier() {
    asm volatile("s_waitcnt lgkmcnt(0)" ::: "memory");
    __builtin_amdgcn_s_barrier();
    asm volatile("" ::: "memory");
}

// 4 h-broadcasts + 4 fmaf into one accumulator chain
#define DOT4(ACC, W, K)                                   \
    do {                                                  \
        ACC = fmaf(W.x, bcast(h, (K) + 0), ACC);          \
        ACC = fmaf(W.y, bcast(h, (K) + 1), ACC);          \
        ACC = fmaf(W.z, bcast(h, (K) + 2), ACC);          \
        ACC = fmaf(W.w, bcast(h, (K) + 3), ACC);          \
    } while (0)

__global__ __launch_bounds__(192, 1) void gru_scan(
    const float* __restrict__ x,      // [B,T]
    const float* __restrict__ W_ih,   // [192] (CIN=1)
    const float* __restrict__ W_hh,   // [192,64]
    const float* __restrict__ b_ih,   // [192]
    const float* __restrict__ b_hh,   // [192]
    float* __restrict__ states)       // [B,T,64]
{
    const int b   = blockIdx.x;
    const int tid = threadIdx.x;
    const int wv  = tid >> 6;         // gate: 0=r, 1=z, 2=n
    const int u   = tid & 63;         // hidden unit (lane)
    const int g   = (wv << 6) + u;    // this thread's gate row

    __shared__ float ghs[2][3][Hv];   // 1.5 KB double-buffered gate exchange

    const float* xb = x + (size_t)b * Tv;
    float*       sb = states + (size_t)b * Tv * Hv;

    // W_hh row g -> 16 named float4 registers (R3-proven resident at 3 waves)
    const float4* Wv = reinterpret_cast<const float4*>(W_hh + (size_t)g * Hv);
    const float4 w0  = Wv[0],  w1  = Wv[1],  w2  = Wv[2],  w3  = Wv[3];
    const float4 w4  = Wv[4],  w5  = Wv[5],  w6  = Wv[6],  w7  = Wv[7];
    const float4 w8  = Wv[8],  w9  = Wv[9],  w10 = Wv[10], w11 = Wv[11];
    const float4 w12 = Wv[12], w13 = Wv[13], w14 = Wv[14], w15 = Wv[15];
    const float bhh_g = b_hh[g];

    // update-phase constants (per lane = unit; identical across the 3 waves)
    const float wih_r = W_ih[u];
    const float wih_z = W_ih[64  + u];
    const float wih_n = W_ih[128 + u];
    const float bih_r = b_ih[u];
    const float bih_z = b_ih[64  + u];
    const float bih_n = b_ih[128 + u];

    float h  = 0.0f;
    float xv = xb[u];                 // x chunk for steps [0,64), per wave

    for (int t0 = 0; t0 < Tv; t0 += 64) {
        // prefetch next x chunk (safe dummy index on the last chunk)
        const int tn = (t0 + 64 < Tv) ? (t0 + 64) : 0;
        const float xv_next = xb[tn + u];

#pragma unroll 2
        for (int tt = 0; tt < 64; ++tt) {
            const int pb = tt & 1;

            // ---- matvec: own gate row . h, via 64-readlane crossbar ----
            // 4 independent accumulator chains; readlane+fmaf interleave
            // gives 8cy spacing per chain >> 4cy fmaf dep latency.
            float a0 = bhh_g, a1 = 0.0f, a2 = 0.0f, a3 = 0.0f;
            DOT4(a0, w0,   0); DOT4(a1, w1,   4); DOT4(a2, w2,   8); DOT4(a3, w3,  12);
            DOT4(a0, w4,  16); DOT4(a1, w5,  20); DOT4(a2, w6,  24); DOT4(a3, w7,  28);
            DOT4(a0, w8,  32); DOT4(a1, w9,  36); DOT4(a2, w10, 40); DOT4(a3, w11, 44);
            DOT4(a0, w12, 48); DOT4(a1, w13, 52); DOT4(a2, w14, 56); DOT4(a3, w15, 60);
            ghs[pb][wv][u] = (a0 + a1) + (a2 + a3);

            // x-dependent gate inputs: independent of h, fill barrier wait
            const float xt  = bcast(xv, tt);
            const float ir  = fmaf(xt, wih_r, bih_r);
            const float iz  = fmaf(xt, wih_z, bih_z);
            const float in_ = fmaf(xt, wih_n, bih_n);

            lds_barrier();            // the only barrier per step (lgkm-only)

            // ---- redundant h-update on all 3 waves (lane = unit) ----
            const float gr = ghs[pb][0][u];
            const float gz = ghs[pb][1][u];
            const float gn = ghs[pb][2][u];

            const float r  = 1.0f / (1.0f + __expf(-(ir + gr)));
            const float z  = 1.0f / (1.0f + __expf(-(iz + gz)));
            const float a  = fmaf(r, gn, in_);
            const float e  = __expf(2.0f * a);          // tanh(a) = 1 - 2/(e+1)
            const float n  = 1.0f - 2.0f / (e + 1.0f);
            h = fmaf(z, h - n, n);                      // (1-z)*n + z*h

            if (wv == 0) sb[(size_t)(t0 + tt) * Hv + u] = h;  // fire-and-forget
        }
        xv = xv_next;
    }
}

// out[i] = states[i,:] . W_out + b_out + x[i],  i in [0, B*T)
__global__ __launch_bounds__(256) void gru_head(
    const float* __restrict__ x,
    const float* __restrict__ states,
    const float* __restrict__ W_out,   // [64]
    const float* __restrict__ b_out,   // [1]
    float* __restrict__ out)
{
    __shared__ float wsm[Hv];
    if (threadIdx.x < Hv) wsm[threadIdx.x] = W_out[threadIdx.x];
    __syncthreads();

    const int i = blockIdx.x * blockDim.x + threadIdx.x;
    if (i >= Bv * Tv) return;

    const float4* s4 = reinterpret_cast<const float4*>(states + (size_t)i * Hv);
    float acc = 0.0f;
#pragma unroll
    for (int k = 0; k < Hv / 4; ++k) {
        const float4 v = s4[k];
        acc = fmaf(v.x, wsm[4*k+0], acc);
        acc = fmaf(v.y, wsm[4*k+1], acc);
        acc = fmaf(v.z, wsm[4*k+2], acc);
        acc = fmaf(v.w, wsm[4*k+3], acc);
    }
    out[i] = acc + b_out[0] + x[i];
}

extern "C" void kernel_launch(void* const* d_in, const int* in_sizes, int n_in,
                              void* d_out, int out_size, void* d_ws, size_t ws_size,
                              hipStream_t stream) {
    const float* x     = (const float*)d_in[0];   // [B,T,1]
    const float* W_ih  = (const float*)d_in[1];   // [192,1]
    const float* W_hh  = (const float*)d_in[2];   // [192,64]
    const float* b_ih  = (const float*)d_in[3];   // [192]
    const float* b_hh  = (const float*)d_in[4];   // [192]
    const float* W_out = (const float*)d_in[5];   // [1,64]
    const float* b_out = (const float*)d_in[6];   // [1]

    float* out    = (float*)d_out;                // [B*T]
    float* states = out + (size_t)Bv * Tv;        // [B*T*H]

    gru_scan<<<Bv, 192, 0, stream>>>(x, W_ih, W_hh, b_ih, b_hh, states);
    gru_head<<<(Bv * Tv + 255) / 256, 256, 0, stream>>>(x, states, W_out, b_out, out);
}